// Round 1
// baseline (699.371 us; speedup 1.0000x reference)
//
#include <hip/hip_runtime.h>

typedef short bf16x8 __attribute__((ext_vector_type(8)));
typedef float f32x4 __attribute__((ext_vector_type(4)));
typedef unsigned short u16;

#define S_LEN 4096
#define D_DIM 256
#define NROW  16384   // B*S

__device__ __forceinline__ u16 f2bf(float f) {
    union { float f; unsigned u; } v; v.f = f;
    unsigned r = v.u + 0x7FFFu + ((v.u >> 16) & 1u);
    return (u16)(r >> 16);
}

// ---------------- Kernel A: QKV projection -------------------------------
// Q[b,s,e] = sum_d x[b,s,d] * W[e,d] + bias[e]
// Writes Qb, Kb row-major bf16 [16384][256]; V transposed into 64-key
// panels: Vt[((b*64+kt)*256 + d)*64 + (s%64)]
__global__ __launch_bounds__(256) void qkv_proj(
    const float* __restrict__ x,
    const float* __restrict__ Wq, const float* __restrict__ bq,
    const float* __restrict__ Wk, const float* __restrict__ bk,
    const float* __restrict__ Wv, const float* __restrict__ bv,
    u16* __restrict__ Qb, u16* __restrict__ Kb, u16* __restrict__ Vt)
{
    __shared__ u16 xs[64][264];   // 64 rows x 256 bf16, +8 pad
    const int tid = threadIdx.x;
    const int r0 = blockIdx.x * 64;

    // stage x tile -> bf16 LDS (coalesced float4 loads)
    #pragma unroll
    for (int i = 0; i < 16; ++i) {
        int c = i * 256 + tid;          // 4096 float4-chunks
        int row = c >> 6;
        int c4 = c & 63;
        float4 v = reinterpret_cast<const float4*>(x + (size_t)(r0 + row) * D_DIM)[c4];
        ushort4 h = make_ushort4(f2bf(v.x), f2bf(v.y), f2bf(v.z), f2bf(v.w));
        *reinterpret_cast<ushort4*>(&xs[row][c4 * 4]) = h;
    }
    __syncthreads();

    const int w  = tid >> 6;
    const int l  = tid & 63;
    const int lr = l & 15;
    const int lg = l >> 4;
    const int c0 = w * 64;              // wave's 64 output cols

    const float* Ws[3] = {Wq, Wk, Wv};
    const float* Bs[3] = {bq, bk, bv};

    for (int m = 0; m < 3; ++m) {
        const float* Wm = Ws[m];
        f32x4 acc[4][4] = {};           // [rowfrag][colfrag]
        #pragma unroll
        for (int kk = 0; kk < 8; ++kk) {
            bf16x8 a[4];
            #pragma unroll
            for (int rf = 0; rf < 4; ++rf)
                a[rf] = *reinterpret_cast<const bf16x8*>(&xs[rf*16 + lr][kk*32 + lg*8]);
            #pragma unroll
            for (int cf = 0; cf < 4; ++cf) {
                const float* wp = Wm + (size_t)(c0 + cf*16 + lr) * D_DIM + kk*32 + lg*8;
                float4 w0 = *reinterpret_cast<const float4*>(wp);
                float4 w1 = *reinterpret_cast<const float4*>(wp + 4);
                union { bf16x8 v; u16 u[8]; } t;
                t.u[0]=f2bf(w0.x); t.u[1]=f2bf(w0.y); t.u[2]=f2bf(w0.z); t.u[3]=f2bf(w0.w);
                t.u[4]=f2bf(w1.x); t.u[5]=f2bf(w1.y); t.u[6]=f2bf(w1.z); t.u[7]=f2bf(w1.w);
                #pragma unroll
                for (int rf = 0; rf < 4; ++rf)
                    acc[rf][cf] = __builtin_amdgcn_mfma_f32_16x16x32_bf16(a[rf], t.v, acc[rf][cf], 0, 0, 0);
            }
        }
        // epilogue: +bias, cvt, store
        #pragma unroll
        for (int cf = 0; cf < 4; ++cf) {
            float bias = Bs[m][c0 + cf*16 + lr];
            #pragma unroll
            for (int rf = 0; rf < 4; ++rf) {
                if (m < 2) {
                    u16* outp = (m == 0) ? Qb : Kb;
                    #pragma unroll
                    for (int r = 0; r < 4; ++r) {
                        int row = r0 + rf*16 + lg*4 + r;   // C/D: row=(l>>4)*4+r
                        outp[(size_t)row * D_DIM + c0 + cf*16 + lr] = f2bf(acc[rf][cf][r] + bias);
                    }
                } else {
                    int d    = c0 + cf*16 + lr;
                    int bidx = r0 >> 12;
                    int kt   = (r0 & 4095) >> 6;
                    int sloc = rf*16 + lg*4;
                    size_t base = ((size_t)((bidx*64 + kt)*256 + d)) * 64 + sloc;
                    ushort4 h = make_ushort4(
                        f2bf(acc[rf][cf][0] + bias), f2bf(acc[rf][cf][1] + bias),
                        f2bf(acc[rf][cf][2] + bias), f2bf(acc[rf][cf][3] + bias));
                    *reinterpret_cast<ushort4*>(&Vt[base]) = h;   // 4 consecutive s
                }
            }
        }
    }
}

// ---------------- Kernel B: column softmax denominators ------------------
// rZ[b,k] = 1 / sum_q exp(s[b,q,k] / 16).  One wave = 16 keys (A operand in
// regs), streams Q as B operand (acc col = q, row = key).
__global__ __launch_bounds__(64) void col_denom(
    const u16* __restrict__ Qb, const u16* __restrict__ Kb, float* __restrict__ rZ)
{
    const int l   = threadIdx.x;
    const int blk = blockIdx.x;                 // 1024 blocks
    const int b   = (blk & 7) >> 1;             // XCD-cluster batches
    const int idx = ((blk >> 3) << 1) | (blk & 1);  // 0..255
    const int k0  = idx * 16;
    const int lr = l & 15, lg = l >> 4;

    bf16x8 kreg[8];
    #pragma unroll
    for (int kk = 0; kk < 8; ++kk)
        kreg[kk] = *reinterpret_cast<const bf16x8*>(
            &Kb[((size_t)(b*S_LEN + k0 + lr)) * D_DIM + kk*32 + lg*8]);

    float Zacc[4] = {0.f, 0.f, 0.f, 0.f};
    const float SC = 0.0625f;                   // 1/sqrt(256)

    for (int qt = 0; qt < 64; ++qt) {
        const int q0 = qt * 64;
        f32x4 acc[4] = {};
        #pragma unroll
        for (int kk = 0; kk < 8; ++kk) {
            #pragma unroll
            for (int cf = 0; cf < 4; ++cf) {
                bf16x8 qf = *reinterpret_cast<const bf16x8*>(
                    &Qb[((size_t)(b*S_LEN + q0 + cf*16 + lr)) * D_DIM + kk*32 + lg*8]);
                acc[cf] = __builtin_amdgcn_mfma_f32_16x16x32_bf16(kreg[kk], qf, acc[cf], 0, 0, 0);
            }
        }
        #pragma unroll
        for (int cf = 0; cf < 4; ++cf)
            #pragma unroll
            for (int r = 0; r < 4; ++r)
                Zacc[r] += __expf(acc[cf][r] * SC);
    }
    #pragma unroll
    for (int r = 0; r < 4; ++r) {
        float z = Zacc[r];
        z += __shfl_xor(z, 1);
        z += __shfl_xor(z, 2);
        z += __shfl_xor(z, 4);
        z += __shfl_xor(z, 8);
        if (lr == 0) rZ[b*S_LEN + k0 + lg*4 + r] = 1.0f / z;
    }
}

// ---------------- Kernel C: out = (exp(S)/Z) @ V --------------------------
// Block: 64 queries (4 waves x 16). Loops 64-key tiles: stage K + V^T panel
// in LDS, scores -> exp*rZ -> P (per-wave LDS) -> PV MFMA.
__global__ __launch_bounds__(256) void attn_out(
    const u16* __restrict__ Qb, const u16* __restrict__ Kb, const u16* __restrict__ Vt,
    const float* __restrict__ rZ, float* __restrict__ out)
{
    __shared__ u16 ks[64][264];      // K tile, +8 pad
    __shared__ u16 vs[256 * 64];     // V^T tile, XOR-swizzled 16B chunks
    __shared__ u16 ps[4][16][88];    // per-wave P tile, 16B-aligned stride

    const int tid = threadIdx.x;
    const int blk = blockIdx.x;                 // 256 blocks
    const int b   = (blk & 7) >> 1;             // XCD-cluster batches
    const int qs  = ((blk >> 3) << 1) | (blk & 1);  // 0..63
    const int w   = tid >> 6;
    const int l   = tid & 63;
    const int lr = l & 15, lg = l >> 4;
    const int q0 = qs * 64 + w * 16;

    // Q rows held in registers for the whole kernel (A-fragments)
    bf16x8 qreg[8];
    #pragma unroll
    for (int kk = 0; kk < 8; ++kk)
        qreg[kk] = *reinterpret_cast<const bf16x8*>(
            &Qb[((size_t)(b*S_LEN + q0 + lr)) * D_DIM + kk*32 + lg*8]);

    f32x4 oacc[16] = {};
    const float SC = 0.0625f;

    for (int kt = 0; kt < 64; ++kt) {
        const int kbase = kt * 64;
        // stage K tile (coalesced 16B)
        {
            const u16* src = Kb + ((size_t)(b*S_LEN + kbase)) * D_DIM;
            #pragma unroll
            for (int i = 0; i < 8; ++i) {
                int c = i*256 + tid;            // 2048 chunks of 8 elems
                int row = c >> 5, c8 = c & 31;
                *reinterpret_cast<int4*>(&ks[row][c8*8]) =
                    *reinterpret_cast<const int4*>(src + (size_t)row * D_DIM + c8*8);
            }
            // stage V^T panel (contiguous global; XOR-swizzled LDS chunks)
            const u16* vsrc = Vt + ((size_t)(b*64 + kt)) * 256 * 64;
            #pragma unroll
            for (int i = 0; i < 8; ++i) {
                int c = i*256 + tid;
                int d = c >> 3, c8 = c & 7;
                int sw = c8 ^ (d & 7);
                *reinterpret_cast<int4*>(&vs[d*64 + sw*8]) =
                    *reinterpret_cast<const int4*>(vsrc + (size_t)c * 8);
            }
        }
        __syncthreads();

        // scores: acc col = key, row = query
        f32x4 sacc[4] = {};
        #pragma unroll
        for (int kk = 0; kk < 8; ++kk) {
            #pragma unroll
            for (int cf = 0; cf < 4; ++cf) {
                bf16x8 kf = *reinterpret_cast<const bf16x8*>(&ks[cf*16 + lr][kk*32 + lg*8]);
                sacc[cf] = __builtin_amdgcn_mfma_f32_16x16x32_bf16(qreg[kk], kf, sacc[cf], 0, 0, 0);
            }
        }
        // P = exp(s/16) * rZ[k]  -> per-wave LDS (bf16)
        #pragma unroll
        for (int cf = 0; cf < 4; ++cf) {
            float rz = rZ[b*S_LEN + kbase + cf*16 + lr];
            #pragma unroll
            for (int r = 0; r < 4; ++r) {
                float p = __expf(sacc[cf][r] * SC) * rz;
                ps[w][lg*4 + r][cf*16 + lr] = f2bf(p);
            }
        }
        // PV: out += P @ V   (A from ps, B from swizzled vs)
        #pragma unroll
        for (int kk2 = 0; kk2 < 2; ++kk2) {
            bf16x8 af = *reinterpret_cast<const bf16x8*>(&ps[w][lr][kk2*32 + lg*8]);
            #pragma unroll
            for (int cf2 = 0; cf2 < 16; ++cf2) {
                int d = cf2*16 + lr;
                int sw = (kk2*4 + lg) ^ (d & 7);
                bf16x8 vf = *reinterpret_cast<const bf16x8*>(&vs[d*64 + sw*8]);
                oacc[cf2] = __builtin_amdgcn_mfma_f32_16x16x32_bf16(af, vf, oacc[cf2], 0, 0, 0);
            }
        }
        __syncthreads();
    }

    // write out (f32)
    #pragma unroll
    for (int cf2 = 0; cf2 < 16; ++cf2) {
        #pragma unroll
        for (int r = 0; r < 4; ++r) {
            int row = q0 + lg*4 + r;
            out[((size_t)(b*S_LEN + row)) * D_DIM + cf2*16 + lr] = oacc[cf2][r];
        }
    }
}

// ---------------- launcher ------------------------------------------------
extern "C" void kernel_launch(void* const* d_in, const int* in_sizes, int n_in,
                              void* d_out, int out_size, void* d_ws, size_t ws_size,
                              hipStream_t stream) {
    const float* x  = (const float*)d_in[0];
    const float* Wq = (const float*)d_in[1];
    const float* bq = (const float*)d_in[2];
    const float* Wk = (const float*)d_in[3];
    const float* bk = (const float*)d_in[4];
    const float* Wv = (const float*)d_in[5];
    const float* bv = (const float*)d_in[6];
    float* out = (float*)d_out;

    u16* Qb = (u16*)d_ws;                 // 16384*256 bf16
    u16* Kb = Qb + (size_t)NROW * D_DIM;
    u16* Vt = Kb + (size_t)NROW * D_DIM;  // transposed V panels
    float* rZ = (float*)(Vt + (size_t)NROW * D_DIM);  // 4*4096 f32

    qkv_proj<<<NROW / 64, 256, 0, stream>>>(x, Wq, bq, Wk, bk, Wv, bv, Qb, Kb, Vt);
    col_denom<<<1024, 64, 0, stream>>>(Qb, Kb, rZ);
    attn_out<<<256, 256, 0, stream>>>(Qb, Kb, Vt, rZ, out);
}